// Round 9
// baseline (505.769 us; speedup 1.0000x reference)
//
#include <hip/hip_runtime.h>
#include <hip/hip_fp16.h>
#include <math.h>

#define NN 100000
#define DD 128
#define SCAN_CHUNK 2048

typedef short short8 __attribute__((ext_vector_type(8)));
typedef float f32x4 __attribute__((ext_vector_type(4)));

// ---------------- degree histogram + per-edge rank ----------------
__global__ __launch_bounds__(256) void hist_rank_kernel(const int* __restrict__ dst, int E,
                                                        int* __restrict__ deg,
                                                        int* __restrict__ rank) {
    int i = blockIdx.x * 256 + threadIdx.x;
    int e = i * 4;
    if (e + 3 < E) {
        int4 d4 = ((const int4*)dst)[i];
        int4 r4;
        r4.x = atomicAdd(&deg[d4.x], 1);
        r4.y = atomicAdd(&deg[d4.y], 1);
        r4.z = atomicAdd(&deg[d4.z], 1);
        r4.w = atomicAdd(&deg[d4.w], 1);
        ((int4*)rank)[i] = r4;
    } else {
        for (; e < E; ++e) rank[e] = atomicAdd(&deg[dst[e]], 1);
    }
}

// ---------------- scan part 1: per-chunk sums (+ fused dinv) ----------------
__global__ __launch_bounds__(256) void scan1_kernel(const int* __restrict__ deg,
                                                    int* __restrict__ chunkSum,
                                                    float* __restrict__ dinv, int n) {
    __shared__ int lds[256];
    int tid = threadIdx.x;
    int base = blockIdx.x * SCAN_CHUNK + tid * 8;
    int s = 0;
    #pragma unroll
    for (int j = 0; j < 8; ++j) {
        int idx = base + j;
        if (idx < n) {
            int d = deg[idx];
            s += d;
            dinv[idx] = rsqrtf((float)d + 1.0f);
        }
    }
    lds[tid] = s;
    __syncthreads();
    for (int d = 128; d > 0; d >>= 1) {
        if (tid < d) lds[tid] += lds[tid + d];
        __syncthreads();
    }
    if (tid == 0) chunkSum[blockIdx.x] = lds[0];
}

// ---------------- scan part 2 ----------------
__global__ void scan2_kernel(int* __restrict__ chunkSum, int* __restrict__ chunkOff,
                             int nb, int* __restrict__ offsets) {
    __shared__ int lds[512];
    int tid = threadIdx.x;
    if (tid < nb) lds[tid] = chunkSum[tid];
    __syncthreads();
    if (tid == 0) {
        int run = 0;
        for (int i = 0; i < nb; ++i) {
            int v = lds[i];
            lds[i] = run;
            run += v;
        }
        offsets[NN] = run;
    }
    __syncthreads();
    if (tid < nb) chunkOff[tid] = lds[tid];
}

// ---------------- scan part 3 ----------------
__global__ __launch_bounds__(256) void scan3_kernel(const int* __restrict__ deg,
                                                    const int* __restrict__ chunkOff,
                                                    int* __restrict__ offsets, int n) {
    __shared__ int lds[256];
    int tid = threadIdx.x;
    int base = blockIdx.x * SCAN_CHUNK + tid * 8;
    int v[8];
    int tsum = 0;
    #pragma unroll
    for (int j = 0; j < 8; ++j) {
        int idx = base + j;
        v[j] = (idx < n) ? deg[idx] : 0;
        tsum += v[j];
    }
    lds[tid] = tsum;
    __syncthreads();
    for (int d = 1; d < 256; d <<= 1) {
        int t = (tid >= d) ? lds[tid - d] : 0;
        __syncthreads();
        lds[tid] += t;
        __syncthreads();
    }
    int excl = lds[tid] - tsum;
    int off0 = chunkOff[blockIdx.x] + excl;
    int run = 0;
    #pragma unroll
    for (int j = 0; j < 8; ++j) {
        int idx = base + j;
        if (idx < n) offsets[idx] = off0 + run;
        run += v[j];
    }
}

// ---------------- CSR fill (atomic-free) ----------------
__global__ __launch_bounds__(256) void fill_kernel(const int* __restrict__ src,
                                                   const int* __restrict__ dst,
                                                   const int* __restrict__ rank, int E,
                                                   const int* __restrict__ offsets,
                                                   int* __restrict__ csr) {
    int i = blockIdx.x * 256 + threadIdx.x;
    int e = i * 4;
    if (e + 3 < E) {
        int4 d4 = ((const int4*)dst)[i];
        int4 s4 = ((const int4*)src)[i];
        int4 r4 = ((const int4*)rank)[i];
        int o0 = offsets[d4.x];
        int o1 = offsets[d4.y];
        int o2 = offsets[d4.z];
        int o3 = offsets[d4.w];
        csr[o0 + r4.x] = s4.x;
        csr[o1 + r4.y] = s4.y;
        csr[o2 + r4.z] = s4.z;
        csr[o3 + r4.w] = s4.w;
    } else {
        for (; e < E; ++e) csr[offsets[dst[e]] + rank[e]] = src[e];
    }
}

// ---------------- helpers: fp32 -> bf16 split ----------------
__device__ __forceinline__ unsigned short f2bf(float f) {
    unsigned int u = __float_as_uint(f);
    unsigned int r = u + 0x7FFFu + ((u >> 16) & 1u);
    return (unsigned short)(r >> 16);
}

__device__ __forceinline__ void split8(const float* v, short8& hi, short8& lo) {
    #pragma unroll
    for (int j = 0; j < 8; ++j) {
        float f = v[j];
        unsigned short h = f2bf(f);
        float fl = f - __uint_as_float(((unsigned int)h) << 16);
        hi[j] = (short)h;
        lo[j] = (short)f2bf(fl);
    }
}

// ---------------- W pre-split into fragment-ordered bf16 hi/lo ----------------
// i = (cf*4 + ks)*64 + lane ; lane: n=lane&15, k-sub=lane>>4 (8 k each)
__global__ __launch_bounds__(256) void wsplit_kernel(const float* __restrict__ W,
                                                     uint4* __restrict__ wh,
                                                     uint4* __restrict__ wl) {
    int i = blockIdx.x * 256 + threadIdx.x;      // 0..2047
    int lane_e = i & 63;
    int ks = (i >> 6) & 3;
    int cf = i >> 8;
    int colb = cf * 16 + (lane_e & 15);
    int rowb = ks * 32 + (lane_e >> 4) * 8;
    float wvv[8];
    #pragma unroll
    for (int j = 0; j < 8; ++j) wvv[j] = W[(rowb + j) * DD + colb];
    short8 h, l;
    split8(wvv, h, l);
    union { short8 s; uint4 u; } ch, cl;
    ch.s = h; cl.s = l;
    wh[i] = ch.u;
    wl[i] = cl.u;
}

// ---------------- MFMA GEMM + src-norm fuse: g = fp16((X @ W) * dinv[row]) ----------------
// 128x128 tile, 4 waves. Markidis 2-term bf16 split (pre-split W from global).
__global__ __launch_bounds__(256, 2) void gemm_norm_kernel(
    const float* __restrict__ X, const uint4* __restrict__ whg,
    const uint4* __restrict__ wlg,
    const float* __restrict__ dinv, __half* __restrict__ G)
{
    __shared__ uint4 whf[2048];   // 32 KB
    __shared__ uint4 wlf[2048];   // 32 KB

    const int tid  = threadIdx.x;
    const int base = blockIdx.x * 128;
    const int lane = tid & 63;
    const int wv   = tid >> 6;        // wave 0..3
    const int kg   = lane >> 4;       // k-group 0..3
    const int mcol = lane & 15;       // A-row / D-col

    // ---- stage pre-split W (pure coalesced copy) ----
    #pragma unroll
    for (int p = 0; p < 8; ++p) {
        int i = tid + p * 256;
        whf[i] = whg[i];
        wlf[i] = wlg[i];
    }

    // ---- load A fragments (X) straight from global, split to bf16 hi/lo ----
    short8 ah[2][4], al[2][4];
    #pragma unroll
    for (int rf = 0; rf < 2; ++rf) {
        int arow = base + wv * 32 + rf * 16 + mcol;
        if (arow >= NN) arow = NN - 1;                 // clamp (stores guarded)
        const float* xr = X + (size_t)arow * DD;
        #pragma unroll
        for (int ks = 0; ks < 4; ++ks) {
            int k0 = ks * 32 + kg * 8;
            float av[8];
            *(float4*)&av[0] = *(const float4*)&xr[k0];
            *(float4*)&av[4] = *(const float4*)&xr[k0 + 4];
            split8(av, ah[rf][ks], al[rf][ks]);
        }
    }
    __syncthreads();

    // ---- main loop over 8 column-fragments ----
    #pragma unroll 1
    for (int cf = 0; cf < 8; ++cf) {
        f32x4 acc0 = {0.f, 0.f, 0.f, 0.f};
        f32x4 acc1 = {0.f, 0.f, 0.f, 0.f};
        #pragma unroll
        for (int ks = 0; ks < 4; ++ks) {
            union { uint4 u; short8 s; } bh, bl;
            bh.u = whf[(cf * 4 + ks) * 64 + lane];
            bl.u = wlf[(cf * 4 + ks) * 64 + lane];
            acc0 = __builtin_amdgcn_mfma_f32_16x16x32_bf16(ah[0][ks], bh.s, acc0, 0, 0, 0);
            acc0 = __builtin_amdgcn_mfma_f32_16x16x32_bf16(al[0][ks], bh.s, acc0, 0, 0, 0);
            acc0 = __builtin_amdgcn_mfma_f32_16x16x32_bf16(ah[0][ks], bl.s, acc0, 0, 0, 0);
            acc1 = __builtin_amdgcn_mfma_f32_16x16x32_bf16(ah[1][ks], bh.s, acc1, 0, 0, 0);
            acc1 = __builtin_amdgcn_mfma_f32_16x16x32_bf16(al[1][ks], bh.s, acc1, 0, 0, 0);
            acc1 = __builtin_amdgcn_mfma_f32_16x16x32_bf16(ah[1][ks], bl.s, acc1, 0, 0, 0);
        }
        #pragma unroll
        for (int rf = 0; rf < 2; ++rf) {
            const f32x4 acc = rf ? acc1 : acc0;
            int row0 = base + wv * 32 + rf * 16 + kg * 4;
            if (row0 < NN) {
                float dv[4];
                *(float4*)dv = *(const float4*)&dinv[row0];
                #pragma unroll
                for (int j = 0; j < 4; ++j) {
                    G[(size_t)(row0 + j) * DD + cf * 16 + mcol] =
                        __float2half(acc[j] * dv[j]);
                }
            }
        }
    }
}

// ---------------- gather-aggregate + bias + relu (line-granular half-split) ----------------
// Wave handles (node, half): half h = blockIdx&1 -> even XCDs touch only even
// 128B lines of g, odd XCDs odd lines (per-XCD footprint halves).
// lane: sub=lane>>5 picks 1 of 2 edges per instr; cl=lane&31 spans the 128B half.
__global__ __launch_bounds__(256) void agg_kernel(
    const __half* __restrict__ g, const float* __restrict__ dinv,
    const int* __restrict__ off, const int* __restrict__ csr,
    const float* __restrict__ bias, float* __restrict__ out)
{
    const int tid  = threadIdx.x;
    const int wid  = tid >> 6;
    const int lane = tid & 63;
    const int sub  = lane >> 5;       // 0/1: which edge of the pair
    const int cl   = lane & 31;       // half2 index within the half-line
    const int h    = blockIdx.x & 1;

    int node = (int)(blockIdx.x >> 1) * 4 + wid;
    if (node >= NN) return;

    const __half2* __restrict__ g2 = (const __half2*)g;
    const int colb = h * 32 + cl;

    float2 acc0 = make_float2(0.f, 0.f), acc1 = make_float2(0.f, 0.f);
    if (sub == 0) acc0 = __half22float2(g2[node * 64 + colb]);   // self-loop

    int e = off[node], end = off[node + 1];
    int cnt = end - e;
    int pairs = cnt >> 1;
    int np = pairs & ~3;

    if (np) {
        int i0 = csr[e + 0 + sub];
        int i1 = csr[e + 2 + sub];
        int i2 = csr[e + 4 + sub];
        int i3 = csr[e + 6 + sub];
        for (int p = 4; p < np; p += 4) {
            int b0 = e + 2 * p + sub;
            int j0 = csr[b0];
            int j1 = csr[b0 + 2];
            int j2 = csr[b0 + 4];
            int j3 = csr[b0 + 6];
            float2 v0 = __half22float2(g2[i0 * 64 + colb]);
            float2 v1 = __half22float2(g2[i1 * 64 + colb]);
            float2 v2 = __half22float2(g2[i2 * 64 + colb]);
            float2 v3 = __half22float2(g2[i3 * 64 + colb]);
            acc0.x += v0.x; acc0.y += v0.y;
            acc1.x += v1.x; acc1.y += v1.y;
            acc0.x += v2.x; acc0.y += v2.y;
            acc1.x += v3.x; acc1.y += v3.y;
            i0 = j0; i1 = j1; i2 = j2; i3 = j3;
        }
        float2 v0 = __half22float2(g2[i0 * 64 + colb]);
        float2 v1 = __half22float2(g2[i1 * 64 + colb]);
        float2 v2 = __half22float2(g2[i2 * 64 + colb]);
        float2 v3 = __half22float2(g2[i3 * 64 + colb]);
        acc0.x += v0.x; acc0.y += v0.y;
        acc1.x += v1.x; acc1.y += v1.y;
        acc0.x += v2.x; acc0.y += v2.y;
        acc1.x += v3.x; acc1.y += v3.y;
    }
    for (int q = np; q < pairs; ++q) {
        int s = csr[e + 2 * q + sub];
        float2 v = __half22float2(g2[s * 64 + colb]);
        acc0.x += v.x; acc0.y += v.y;
    }
    if ((cnt & 1) && sub == 0) {
        int s = csr[end - 1];
        float2 v = __half22float2(g2[s * 64 + colb]);
        acc0.x += v.x; acc0.y += v.y;
    }

    acc0.x += acc1.x; acc0.y += acc1.y;
    acc0.x += __shfl_xor(acc0.x, 32, 64);
    acc0.y += __shfl_xor(acc0.y, 32, 64);

    if (sub == 0) {
        float di = dinv[node];
        float2 bb = ((const float2*)bias)[colb];
        float2 o;
        o.x = fmaxf(fmaf(acc0.x, di, bb.x), 0.f);
        o.y = fmaxf(fmaf(acc0.y, di, bb.y), 0.f);
        ((float2*)out)[node * 64 + colb] = o;
    }
}

extern "C" void kernel_launch(void* const* d_in, const int* in_sizes, int n_in,
                              void* d_out, int out_size, void* d_ws, size_t ws_size,
                              hipStream_t stream)
{
    const float* x  = (const float*)d_in[0];
    const float* W1 = (const float*)d_in[1];
    const float* b1 = (const float*)d_in[2];
    const float* W2 = (const float*)d_in[3];
    const float* b2 = (const float*)d_in[4];
    const float* W3 = (const float*)d_in[5];
    const float* b3 = (const float*)d_in[6];
    const int*   ei = (const int*)d_in[7];

    const int E = in_sizes[7] / 2;          // 1,600,000
    const int* src = ei;
    const int* dst = ei + E;

    float* out = (float*)d_out;

    // ---- workspace layout ----
    char* wsb = (char*)d_ws;
    size_t p = 0;
    int* deg      = (int*)(wsb + p); p += ((size_t)NN * 4 + 1023) & ~1023ull;
    int* offsets  = (int*)(wsb + p); p += ((size_t)(NN + 1) * 4 + 1023) & ~1023ull;
    int* chunkSum = (int*)(wsb + p); p += 4096;
    int* chunkOff = (int*)(wsb + p); p += 4096;
    int* csr      = (int*)(wsb + p); p += ((size_t)E * 4 + 1023) & ~1023ull;
    int* rank     = (int*)(wsb + p); p += ((size_t)E * 4 + 1023) & ~1023ull;
    float* dinv   = (float*)(wsb + p); p += ((size_t)NN * 4 + 1023) & ~1023ull;
    uint4* wh     = (uint4*)(wsb + p); p += 3 * 2048 * sizeof(uint4);
    uint4* wl     = (uint4*)(wsb + p); p += 3 * 2048 * sizeof(uint4);
    __half* g     = (__half*)(wsb + p); p += (size_t)NN * DD * 2;

    const int NB = (NN + SCAN_CHUNK - 1) / SCAN_CHUNK;   // 49

    // ---- CSR build + dinv + W pre-split ----
    hipMemsetAsync(deg, 0, (size_t)NN * 4, stream);
    hist_rank_kernel<<<(E / 4 + 256) / 256 + 1, 256, 0, stream>>>(dst, E, deg, rank);
    scan1_kernel<<<NB, 256, 0, stream>>>(deg, chunkSum, dinv, NN);
    scan2_kernel<<<1, 512, 0, stream>>>(chunkSum, chunkOff, NB, offsets);
    scan3_kernel<<<NB, 256, 0, stream>>>(deg, chunkOff, offsets, NN);
    fill_kernel<<<(E / 4 + 256) / 256 + 1, 256, 0, stream>>>(src, dst, rank, E, offsets, csr);
    wsplit_kernel<<<8, 256, 0, stream>>>(W1, wh + 0 * 2048, wl + 0 * 2048);
    wsplit_kernel<<<8, 256, 0, stream>>>(W2, wh + 1 * 2048, wl + 1 * 2048);
    wsplit_kernel<<<8, 256, 0, stream>>>(W3, wh + 2 * 2048, wl + 2 * 2048);

    const int gemm_grid = (NN + 127) / 128;               // 782
    const int agg_grid  = 2 * ((NN + 3) / 4);             // 50000

    // ---- layer 1 ----
    gemm_norm_kernel<<<gemm_grid, 256, 0, stream>>>(x, wh + 0 * 2048, wl + 0 * 2048, dinv, g);
    agg_kernel<<<agg_grid, 256, 0, stream>>>(g, dinv, offsets, csr, b1, out);
    // ---- layer 2 ----
    gemm_norm_kernel<<<gemm_grid, 256, 0, stream>>>(out, wh + 1 * 2048, wl + 1 * 2048, dinv, g);
    agg_kernel<<<agg_grid, 256, 0, stream>>>(g, dinv, offsets, csr, b2, out);
    // ---- layer 3 ----
    gemm_norm_kernel<<<gemm_grid, 256, 0, stream>>>(out, W3 ? wh + 2 * 2048 : wh, wl + 2 * 2048, dinv, g);
    agg_kernel<<<agg_grid, 256, 0, stream>>>(g, dinv, offsets, csr, b3, out);
}

// Round 10
// 404.829 us; speedup vs baseline: 1.2493x; 1.2493x over previous
//
#include <hip/hip_runtime.h>
#include <hip/hip_fp16.h>
#include <math.h>

#define NN 100000
#define DD 128
#define SCAN_CHUNK 2048
#define AGG_BLOCKS 2048

typedef short short8 __attribute__((ext_vector_type(8)));
typedef float f32x4 __attribute__((ext_vector_type(4)));

// ---------------- degree histogram + per-edge rank ----------------
__global__ __launch_bounds__(256) void hist_rank_kernel(const int* __restrict__ dst, int E,
                                                        int* __restrict__ deg,
                                                        int* __restrict__ rank) {
    int i = blockIdx.x * 256 + threadIdx.x;
    int e = i * 4;
    if (e + 3 < E) {
        int4 d4 = ((const int4*)dst)[i];
        int4 r4;
        r4.x = atomicAdd(&deg[d4.x], 1);
        r4.y = atomicAdd(&deg[d4.y], 1);
        r4.z = atomicAdd(&deg[d4.z], 1);
        r4.w = atomicAdd(&deg[d4.w], 1);
        ((int4*)rank)[i] = r4;
    } else {
        for (; e < E; ++e) rank[e] = atomicAdd(&deg[dst[e]], 1);
    }
}

// ---------------- scan part 1: per-chunk sums (+ fused dinv) ----------------
__global__ __launch_bounds__(256) void scan1_kernel(const int* __restrict__ deg,
                                                    int* __restrict__ chunkSum,
                                                    float* __restrict__ dinv, int n) {
    __shared__ int lds[256];
    int tid = threadIdx.x;
    int base = blockIdx.x * SCAN_CHUNK + tid * 8;
    int s = 0;
    #pragma unroll
    for (int j = 0; j < 8; ++j) {
        int idx = base + j;
        if (idx < n) {
            int d = deg[idx];
            s += d;
            dinv[idx] = rsqrtf((float)d + 1.0f);
        }
    }
    lds[tid] = s;
    __syncthreads();
    for (int d = 128; d > 0; d >>= 1) {
        if (tid < d) lds[tid] += lds[tid + d];
        __syncthreads();
    }
    if (tid == 0) chunkSum[blockIdx.x] = lds[0];
}

// ---------------- scan part 2 ----------------
__global__ void scan2_kernel(int* __restrict__ chunkSum, int* __restrict__ chunkOff,
                             int nb, int* __restrict__ offsets) {
    __shared__ int lds[512];
    int tid = threadIdx.x;
    if (tid < nb) lds[tid] = chunkSum[tid];
    __syncthreads();
    if (tid == 0) {
        int run = 0;
        for (int i = 0; i < nb; ++i) {
            int v = lds[i];
            lds[i] = run;
            run += v;
        }
        offsets[NN] = run;
    }
    __syncthreads();
    if (tid < nb) chunkOff[tid] = lds[tid];
}

// ---------------- scan part 3 ----------------
__global__ __launch_bounds__(256) void scan3_kernel(const int* __restrict__ deg,
                                                    const int* __restrict__ chunkOff,
                                                    int* __restrict__ offsets, int n) {
    __shared__ int lds[256];
    int tid = threadIdx.x;
    int base = blockIdx.x * SCAN_CHUNK + tid * 8;
    int v[8];
    int tsum = 0;
    #pragma unroll
    for (int j = 0; j < 8; ++j) {
        int idx = base + j;
        v[j] = (idx < n) ? deg[idx] : 0;
        tsum += v[j];
    }
    lds[tid] = tsum;
    __syncthreads();
    for (int d = 1; d < 256; d <<= 1) {
        int t = (tid >= d) ? lds[tid - d] : 0;
        __syncthreads();
        lds[tid] += t;
        __syncthreads();
    }
    int excl = lds[tid] - tsum;
    int off0 = chunkOff[blockIdx.x] + excl;
    int run = 0;
    #pragma unroll
    for (int j = 0; j < 8; ++j) {
        int idx = base + j;
        if (idx < n) offsets[idx] = off0 + run;
        run += v[j];
    }
}

// ---------------- CSR fill (atomic-free) ----------------
__global__ __launch_bounds__(256) void fill_kernel(const int* __restrict__ src,
                                                   const int* __restrict__ dst,
                                                   const int* __restrict__ rank, int E,
                                                   const int* __restrict__ offsets,
                                                   int* __restrict__ csr) {
    int i = blockIdx.x * 256 + threadIdx.x;
    int e = i * 4;
    if (e + 3 < E) {
        int4 d4 = ((const int4*)dst)[i];
        int4 s4 = ((const int4*)src)[i];
        int4 r4 = ((const int4*)rank)[i];
        int o0 = offsets[d4.x];
        int o1 = offsets[d4.y];
        int o2 = offsets[d4.z];
        int o3 = offsets[d4.w];
        csr[o0 + r4.x] = s4.x;
        csr[o1 + r4.y] = s4.y;
        csr[o2 + r4.z] = s4.z;
        csr[o3 + r4.w] = s4.w;
    } else {
        for (; e < E; ++e) csr[offsets[dst[e]] + rank[e]] = src[e];
    }
}

// ---------------- helpers: fp32 -> bf16 split ----------------
__device__ __forceinline__ unsigned short f2bf(float f) {
    unsigned int u = __float_as_uint(f);
    unsigned int r = u + 0x7FFFu + ((u >> 16) & 1u);
    return (unsigned short)(r >> 16);
}

__device__ __forceinline__ void split8(const float* v, short8& hi, short8& lo) {
    #pragma unroll
    for (int j = 0; j < 8; ++j) {
        float f = v[j];
        unsigned short h = f2bf(f);
        float fl = f - __uint_as_float(((unsigned int)h) << 16);
        hi[j] = (short)h;
        lo[j] = (short)f2bf(fl);
    }
}

// ---------------- W pre-split (all 3 layers, one launch) ----------------
__global__ __launch_bounds__(256) void wsplit3_kernel(const float* __restrict__ W1,
                                                      const float* __restrict__ W2,
                                                      const float* __restrict__ W3,
                                                      uint4* __restrict__ wh,
                                                      uint4* __restrict__ wl) {
    int b = blockIdx.x;              // 0..23
    int layer = b >> 3;
    const float* W = (layer == 0) ? W1 : (layer == 1) ? W2 : W3;
    int i = (b & 7) * 256 + threadIdx.x;      // 0..2047
    int lane_e = i & 63;
    int ks = (i >> 6) & 3;
    int cf = i >> 8;
    int colb = cf * 16 + (lane_e & 15);
    int rowb = ks * 32 + (lane_e >> 4) * 8;
    float wvv[8];
    #pragma unroll
    for (int j = 0; j < 8; ++j) wvv[j] = W[(rowb + j) * DD + colb];
    short8 h, l;
    split8(wvv, h, l);
    union { short8 s; uint4 u; } ch, cl;
    ch.s = h; cl.s = l;
    wh[layer * 2048 + i] = ch.u;
    wl[layer * 2048 + i] = cl.u;
}

// ---------------- MFMA GEMM + src-norm fuse: g = fp16((X @ W) * dinv[row]) ----------------
// 128x128 tile, 4 waves. Markidis 2-term bf16 split. InT = float or __half.
template <typename InT>
__global__ __launch_bounds__(256, 2) void gemm_norm_kernel(
    const InT* __restrict__ X, const uint4* __restrict__ whg,
    const uint4* __restrict__ wlg,
    const float* __restrict__ dinv, __half* __restrict__ G)
{
    __shared__ uint4 whf[2048];   // 32 KB
    __shared__ uint4 wlf[2048];   // 32 KB

    const int tid  = threadIdx.x;
    const int base = blockIdx.x * 128;
    const int lane = tid & 63;
    const int wv   = tid >> 6;        // wave 0..3
    const int kg   = lane >> 4;       // k-group 0..3
    const int mcol = lane & 15;       // A-row / D-col

    // ---- stage pre-split W (pure coalesced copy) ----
    #pragma unroll
    for (int p = 0; p < 8; ++p) {
        int i = tid + p * 256;
        whf[i] = whg[i];
        wlf[i] = wlg[i];
    }

    // ---- load A fragments (X) straight from global, split to bf16 hi/lo ----
    short8 ah[2][4], al[2][4];
    #pragma unroll
    for (int rf = 0; rf < 2; ++rf) {
        int arow = base + wv * 32 + rf * 16 + mcol;
        if (arow >= NN) arow = NN - 1;                 // clamp (stores guarded)
        const InT* xr = X + (size_t)arow * DD;
        #pragma unroll
        for (int ks = 0; ks < 4; ++ks) {
            int k0 = ks * 32 + kg * 8;
            float av[8];
            if constexpr (sizeof(InT) == 4) {
                *(float4*)&av[0] = *(const float4*)&xr[k0];
                *(float4*)&av[4] = *(const float4*)&xr[k0 + 4];
            } else {
                union { uint4 u; __half h[8]; } hv;
                hv.u = *(const uint4*)&xr[k0];
                #pragma unroll
                for (int j = 0; j < 8; ++j) av[j] = __half2float(hv.h[j]);
            }
            split8(av, ah[rf][ks], al[rf][ks]);
        }
    }
    __syncthreads();

    // ---- main loop over 8 column-fragments ----
    #pragma unroll 1
    for (int cf = 0; cf < 8; ++cf) {
        f32x4 acc0 = {0.f, 0.f, 0.f, 0.f};
        f32x4 acc1 = {0.f, 0.f, 0.f, 0.f};
        #pragma unroll
        for (int ks = 0; ks < 4; ++ks) {
            union { uint4 u; short8 s; } bh, bl;
            bh.u = whf[(cf * 4 + ks) * 64 + lane];
            bl.u = wlf[(cf * 4 + ks) * 64 + lane];
            acc0 = __builtin_amdgcn_mfma_f32_16x16x32_bf16(ah[0][ks], bh.s, acc0, 0, 0, 0);
            acc0 = __builtin_amdgcn_mfma_f32_16x16x32_bf16(al[0][ks], bh.s, acc0, 0, 0, 0);
            acc0 = __builtin_amdgcn_mfma_f32_16x16x32_bf16(ah[0][ks], bl.s, acc0, 0, 0, 0);
            acc1 = __builtin_amdgcn_mfma_f32_16x16x32_bf16(ah[1][ks], bh.s, acc1, 0, 0, 0);
            acc1 = __builtin_amdgcn_mfma_f32_16x16x32_bf16(al[1][ks], bh.s, acc1, 0, 0, 0);
            acc1 = __builtin_amdgcn_mfma_f32_16x16x32_bf16(ah[1][ks], bl.s, acc1, 0, 0, 0);
        }
        #pragma unroll
        for (int rf = 0; rf < 2; ++rf) {
            const f32x4 acc = rf ? acc1 : acc0;
            int row0 = base + wv * 32 + rf * 16 + kg * 4;
            if (row0 < NN) {
                float dv[4];
                *(float4*)dv = *(const float4*)&dinv[row0];
                #pragma unroll
                for (int j = 0; j < 4; ++j) {
                    G[(size_t)(row0 + j) * DD + cf * 16 + mcol] =
                        __float2half(acc[j] * dv[j]);
                }
            }
        }
    }
}

// ---------------- gather-aggregate + bias + relu ----------------
// round-6 loop shape (1 edge x 256B per instr, 8-deep pipeline), persistent
// grid-stride blocks (AGG_BLOCKS resident), OutT = __half (layers 1-2) or float.
template <typename OutT>
__global__ __launch_bounds__(256) void agg_kernel(
    const __half* __restrict__ g, const float* __restrict__ dinv,
    const int* __restrict__ off, const int* __restrict__ csr,
    const float* __restrict__ bias, OutT* __restrict__ out)
{
    const int wid  = threadIdx.x >> 6;
    const int lane = threadIdx.x & 63;
    const __half2* __restrict__ g2 = (const __half2*)g;
    const float2 bb = ((const float2*)bias)[lane];
    const int ngroups = (NN + 3) / 4;

    for (int grp = blockIdx.x; grp < ngroups; grp += AGG_BLOCKS) {
        int node = grp * 4 + wid;
        if (node >= NN) continue;

        float2 acc0 = __half22float2(g2[node * 64 + lane]);   // self-loop
        float2 acc1 = make_float2(0.f, 0.f);

        int e = off[node], end = off[node + 1];
        int cnt = end - e;
        int e8end = e + (cnt & ~7);

        if (e < e8end) {
            int idx[8];
            #pragma unroll
            for (int j = 0; j < 8; ++j) idx[j] = csr[e + j];
            e += 8;
            for (; e < e8end; e += 8) {
                int nidx[8];
                #pragma unroll
                for (int j = 0; j < 8; ++j) nidx[j] = csr[e + j];
                #pragma unroll
                for (int j = 0; j < 8; j += 2) {
                    float2 v0 = __half22float2(g2[idx[j] * 64 + lane]);
                    float2 v1 = __half22float2(g2[idx[j + 1] * 64 + lane]);
                    acc0.x += v0.x; acc0.y += v0.y;
                    acc1.x += v1.x; acc1.y += v1.y;
                }
                #pragma unroll
                for (int j = 0; j < 8; ++j) idx[j] = nidx[j];
            }
            #pragma unroll
            for (int j = 0; j < 8; j += 2) {
                float2 v0 = __half22float2(g2[idx[j] * 64 + lane]);
                float2 v1 = __half22float2(g2[idx[j + 1] * 64 + lane]);
                acc0.x += v0.x; acc0.y += v0.y;
                acc1.x += v1.x; acc1.y += v1.y;
            }
        }
        for (; e < end; ++e) {
            float2 v = __half22float2(g2[csr[e] * 64 + lane]);
            acc0.x += v.x; acc0.y += v.y;
        }

        float di = dinv[node];
        float ox = fmaxf(fmaf(acc0.x + acc1.x, di, bb.x), 0.f);
        float oy = fmaxf(fmaf(acc0.y + acc1.y, di, bb.y), 0.f);
        if constexpr (sizeof(OutT) == 4) {
            ((float2*)out)[node * 64 + lane] = make_float2(ox, oy);
        } else {
            ((__half2*)out)[node * 64 + lane] = __floats2half2_rn(ox, oy);
        }
    }
}

extern "C" void kernel_launch(void* const* d_in, const int* in_sizes, int n_in,
                              void* d_out, int out_size, void* d_ws, size_t ws_size,
                              hipStream_t stream)
{
    const float* x  = (const float*)d_in[0];
    const float* W1 = (const float*)d_in[1];
    const float* b1 = (const float*)d_in[2];
    const float* W2 = (const float*)d_in[3];
    const float* b2 = (const float*)d_in[4];
    const float* W3 = (const float*)d_in[5];
    const float* b3 = (const float*)d_in[6];
    const int*   ei = (const int*)d_in[7];

    const int E = in_sizes[7] / 2;          // 1,600,000
    const int* src = ei;
    const int* dst = ei + E;

    float* out = (float*)d_out;

    // ---- workspace layout ----
    char* wsb = (char*)d_ws;
    size_t p = 0;
    int* deg      = (int*)(wsb + p); p += ((size_t)NN * 4 + 1023) & ~1023ull;
    int* offsets  = (int*)(wsb + p); p += ((size_t)(NN + 1) * 4 + 1023) & ~1023ull;
    int* chunkSum = (int*)(wsb + p); p += 4096;
    int* chunkOff = (int*)(wsb + p); p += 4096;
    int* csr      = (int*)(wsb + p); p += ((size_t)E * 4 + 1023) & ~1023ull;
    int* rank     = (int*)(wsb + p); p += ((size_t)E * 4 + 1023) & ~1023ull;
    float* dinv   = (float*)(wsb + p); p += ((size_t)NN * 4 + 1023) & ~1023ull;
    uint4* wh     = (uint4*)(wsb + p); p += 3 * 2048 * sizeof(uint4);
    uint4* wl     = (uint4*)(wsb + p); p += 3 * 2048 * sizeof(uint4);
    __half* g     = (__half*)(wsb + p); p += (size_t)NN * DD * 2;
    __half* h_act = (__half*)(wsb + p); p += (size_t)NN * DD * 2;

    const int NB = (NN + SCAN_CHUNK - 1) / SCAN_CHUNK;   // 49

    // ---- CSR build + dinv + W pre-split ----
    hipMemsetAsync(deg, 0, (size_t)NN * 4, stream);
    hist_rank_kernel<<<(E / 4 + 256) / 256 + 1, 256, 0, stream>>>(dst, E, deg, rank);
    scan1_kernel<<<NB, 256, 0, stream>>>(deg, chunkSum, dinv, NN);
    scan2_kernel<<<1, 512, 0, stream>>>(chunkSum, chunkOff, NB, offsets);
    scan3_kernel<<<NB, 256, 0, stream>>>(deg, chunkOff, offsets, NN);
    fill_kernel<<<(E / 4 + 256) / 256 + 1, 256, 0, stream>>>(src, dst, rank, E, offsets, csr);
    wsplit3_kernel<<<24, 256, 0, stream>>>(W1, W2, W3, wh, wl);

    const int gemm_grid = (NN + 127) / 128;               // 782

    // ---- layer 1 ----
    gemm_norm_kernel<float><<<gemm_grid, 256, 0, stream>>>(x, wh, wl, dinv, g);
    agg_kernel<__half><<<AGG_BLOCKS, 256, 0, stream>>>(g, dinv, offsets, csr, b1, h_act);
    // ---- layer 2 ----
    gemm_norm_kernel<__half><<<gemm_grid, 256, 0, stream>>>(h_act, wh + 2048, wl + 2048, dinv, g);
    agg_kernel<__half><<<AGG_BLOCKS, 256, 0, stream>>>(g, dinv, offsets, csr, b2, h_act);
    // ---- layer 3 ----
    gemm_norm_kernel<__half><<<gemm_grid, 256, 0, stream>>>(h_act, wh + 4096, wl + 4096, dinv, g);
    agg_kernel<float><<<AGG_BLOCKS, 256, 0, stream>>>(g, dinv, offsets, csr, b3, out);
}

// Round 11
// 388.294 us; speedup vs baseline: 1.3025x; 1.0426x over previous
//
#include <hip/hip_runtime.h>
#include <hip/hip_fp16.h>
#include <math.h>

#define NN 100000
#define DD 128
#define SCAN_CHUNK 2048
#define AGG_BLOCKS 2048

typedef short short8 __attribute__((ext_vector_type(8)));
typedef float f32x4 __attribute__((ext_vector_type(4)));

// ---------------- degree histogram + per-edge rank ----------------
__global__ __launch_bounds__(256) void hist_rank_kernel(const int* __restrict__ dst, int E,
                                                        int* __restrict__ deg,
                                                        int* __restrict__ rank) {
    int i = blockIdx.x * 256 + threadIdx.x;
    int e = i * 4;
    if (e + 3 < E) {
        int4 d4 = ((const int4*)dst)[i];
        int4 r4;
        r4.x = atomicAdd(&deg[d4.x], 1);
        r4.y = atomicAdd(&deg[d4.y], 1);
        r4.z = atomicAdd(&deg[d4.z], 1);
        r4.w = atomicAdd(&deg[d4.w], 1);
        ((int4*)rank)[i] = r4;
    } else {
        for (; e < E; ++e) rank[e] = atomicAdd(&deg[dst[e]], 1);
    }
}

// ---------------- scan part 1: per-chunk sums (+ fused dinv) ----------------
__global__ __launch_bounds__(256) void scan1_kernel(const int* __restrict__ deg,
                                                    int* __restrict__ chunkSum,
                                                    float* __restrict__ dinv, int n) {
    __shared__ int lds[256];
    int tid = threadIdx.x;
    int base = blockIdx.x * SCAN_CHUNK + tid * 8;
    int s = 0;
    #pragma unroll
    for (int j = 0; j < 8; ++j) {
        int idx = base + j;
        if (idx < n) {
            int d = deg[idx];
            s += d;
            dinv[idx] = rsqrtf((float)d + 1.0f);
        }
    }
    lds[tid] = s;
    __syncthreads();
    for (int d = 128; d > 0; d >>= 1) {
        if (tid < d) lds[tid] += lds[tid + d];
        __syncthreads();
    }
    if (tid == 0) chunkSum[blockIdx.x] = lds[0];
}

// ---------------- scan part 2 ----------------
__global__ void scan2_kernel(int* __restrict__ chunkSum, int* __restrict__ chunkOff,
                             int nb, int* __restrict__ offsets) {
    __shared__ int lds[512];
    int tid = threadIdx.x;
    if (tid < nb) lds[tid] = chunkSum[tid];
    __syncthreads();
    if (tid == 0) {
        int run = 0;
        for (int i = 0; i < nb; ++i) {
            int v = lds[i];
            lds[i] = run;
            run += v;
        }
        offsets[NN] = run;
    }
    __syncthreads();
    if (tid < nb) chunkOff[tid] = lds[tid];
}

// ---------------- scan part 3 ----------------
__global__ __launch_bounds__(256) void scan3_kernel(const int* __restrict__ deg,
                                                    const int* __restrict__ chunkOff,
                                                    int* __restrict__ offsets, int n) {
    __shared__ int lds[256];
    int tid = threadIdx.x;
    int base = blockIdx.x * SCAN_CHUNK + tid * 8;
    int v[8];
    int tsum = 0;
    #pragma unroll
    for (int j = 0; j < 8; ++j) {
        int idx = base + j;
        v[j] = (idx < n) ? deg[idx] : 0;
        tsum += v[j];
    }
    lds[tid] = tsum;
    __syncthreads();
    for (int d = 1; d < 256; d <<= 1) {
        int t = (tid >= d) ? lds[tid - d] : 0;
        __syncthreads();
        lds[tid] += t;
        __syncthreads();
    }
    int excl = lds[tid] - tsum;
    int off0 = chunkOff[blockIdx.x] + excl;
    int run = 0;
    #pragma unroll
    for (int j = 0; j < 8; ++j) {
        int idx = base + j;
        if (idx < n) offsets[idx] = off0 + run;
        run += v[j];
    }
}

// ---------------- CSR fill (atomic-free) ----------------
__global__ __launch_bounds__(256) void fill_kernel(const int* __restrict__ src,
                                                   const int* __restrict__ dst,
                                                   const int* __restrict__ rank, int E,
                                                   const int* __restrict__ offsets,
                                                   int* __restrict__ csr) {
    int i = blockIdx.x * 256 + threadIdx.x;
    int e = i * 4;
    if (e + 3 < E) {
        int4 d4 = ((const int4*)dst)[i];
        int4 s4 = ((const int4*)src)[i];
        int4 r4 = ((const int4*)rank)[i];
        int o0 = offsets[d4.x];
        int o1 = offsets[d4.y];
        int o2 = offsets[d4.z];
        int o3 = offsets[d4.w];
        csr[o0 + r4.x] = s4.x;
        csr[o1 + r4.y] = s4.y;
        csr[o2 + r4.z] = s4.z;
        csr[o3 + r4.w] = s4.w;
    } else {
        for (; e < E; ++e) csr[offsets[dst[e]] + rank[e]] = src[e];
    }
}

// ---------------- helpers: fp32 -> bf16 split ----------------
__device__ __forceinline__ unsigned short f2bf(float f) {
    unsigned int u = __float_as_uint(f);
    unsigned int r = u + 0x7FFFu + ((u >> 16) & 1u);
    return (unsigned short)(r >> 16);
}

__device__ __forceinline__ void split8(const float* v, short8& hi, short8& lo) {
    #pragma unroll
    for (int j = 0; j < 8; ++j) {
        float f = v[j];
        unsigned short h = f2bf(f);
        float fl = f - __uint_as_float(((unsigned int)h) << 16);
        hi[j] = (short)h;
        lo[j] = (short)f2bf(fl);
    }
}

// ---------------- W pre-split (all 3 layers, one launch) ----------------
__global__ __launch_bounds__(256) void wsplit3_kernel(const float* __restrict__ W1,
                                                      const float* __restrict__ W2,
                                                      const float* __restrict__ W3,
                                                      uint4* __restrict__ wh,
                                                      uint4* __restrict__ wl) {
    int b = blockIdx.x;              // 0..23
    int layer = b >> 3;
    const float* W = (layer == 0) ? W1 : (layer == 1) ? W2 : W3;
    int i = (b & 7) * 256 + threadIdx.x;      // 0..2047
    int lane_e = i & 63;
    int ks = (i >> 6) & 3;
    int cf = i >> 8;
    int colb = cf * 16 + (lane_e & 15);
    int rowb = ks * 32 + (lane_e >> 4) * 8;
    float wvv[8];
    #pragma unroll
    for (int j = 0; j < 8; ++j) wvv[j] = W[(rowb + j) * DD + colb];
    short8 h, l;
    split8(wvv, h, l);
    union { short8 s; uint4 u; } ch, cl;
    ch.s = h; cl.s = l;
    wh[layer * 2048 + i] = ch.u;
    wl[layer * 2048 + i] = cl.u;
}

// ---------------- MFMA GEMM + src-norm fuse: g = fp16((X @ W) * dinv[row]) ----------------
// 128x128 tile, 4 waves. Markidis 2-term bf16 split. InT = float or __half.
template <typename InT>
__global__ __launch_bounds__(256, 2) void gemm_norm_kernel(
    const InT* __restrict__ X, const uint4* __restrict__ whg,
    const uint4* __restrict__ wlg,
    const float* __restrict__ dinv, __half* __restrict__ G)
{
    __shared__ uint4 whf[2048];   // 32 KB
    __shared__ uint4 wlf[2048];   // 32 KB

    const int tid  = threadIdx.x;
    const int base = blockIdx.x * 128;
    const int lane = tid & 63;
    const int wv   = tid >> 6;        // wave 0..3
    const int kg   = lane >> 4;       // k-group 0..3
    const int mcol = lane & 15;       // A-row / D-col

    // ---- stage pre-split W (pure coalesced copy) ----
    #pragma unroll
    for (int p = 0; p < 8; ++p) {
        int i = tid + p * 256;
        whf[i] = whg[i];
        wlf[i] = wlg[i];
    }

    // ---- load A fragments (X) straight from global, split to bf16 hi/lo ----
    short8 ah[2][4], al[2][4];
    #pragma unroll
    for (int rf = 0; rf < 2; ++rf) {
        int arow = base + wv * 32 + rf * 16 + mcol;
        if (arow >= NN) arow = NN - 1;                 // clamp (stores guarded)
        const InT* xr = X + (size_t)arow * DD;
        #pragma unroll
        for (int ks = 0; ks < 4; ++ks) {
            int k0 = ks * 32 + kg * 8;
            float av[8];
            if constexpr (sizeof(InT) == 4) {
                *(float4*)&av[0] = *(const float4*)&xr[k0];
                *(float4*)&av[4] = *(const float4*)&xr[k0 + 4];
            } else {
                union { uint4 u; __half h[8]; } hv;
                hv.u = *(const uint4*)&xr[k0];
                #pragma unroll
                for (int j = 0; j < 8; ++j) av[j] = __half2float(hv.h[j]);
            }
            split8(av, ah[rf][ks], al[rf][ks]);
        }
    }
    __syncthreads();

    // ---- main loop over 8 column-fragments ----
    #pragma unroll 1
    for (int cf = 0; cf < 8; ++cf) {
        f32x4 acc0 = {0.f, 0.f, 0.f, 0.f};
        f32x4 acc1 = {0.f, 0.f, 0.f, 0.f};
        #pragma unroll
        for (int ks = 0; ks < 4; ++ks) {
            union { uint4 u; short8 s; } bh, bl;
            bh.u = whf[(cf * 4 + ks) * 64 + lane];
            bl.u = wlf[(cf * 4 + ks) * 64 + lane];
            acc0 = __builtin_amdgcn_mfma_f32_16x16x32_bf16(ah[0][ks], bh.s, acc0, 0, 0, 0);
            acc0 = __builtin_amdgcn_mfma_f32_16x16x32_bf16(al[0][ks], bh.s, acc0, 0, 0, 0);
            acc0 = __builtin_amdgcn_mfma_f32_16x16x32_bf16(ah[0][ks], bl.s, acc0, 0, 0, 0);
            acc1 = __builtin_amdgcn_mfma_f32_16x16x32_bf16(ah[1][ks], bh.s, acc1, 0, 0, 0);
            acc1 = __builtin_amdgcn_mfma_f32_16x16x32_bf16(al[1][ks], bh.s, acc1, 0, 0, 0);
            acc1 = __builtin_amdgcn_mfma_f32_16x16x32_bf16(ah[1][ks], bl.s, acc1, 0, 0, 0);
        }
        #pragma unroll
        for (int rf = 0; rf < 2; ++rf) {
            const f32x4 acc = rf ? acc1 : acc0;
            int row0 = base + wv * 32 + rf * 16 + kg * 4;
            if (row0 < NN) {
                float dv[4];
                *(float4*)dv = *(const float4*)&dinv[row0];
                #pragma unroll
                for (int j = 0; j < 4; ++j) {
                    G[(size_t)(row0 + j) * DD + cf * 16 + mcol] =
                        __float2half(acc[j] * dv[j]);
                }
            }
        }
    }
}

// ---------------- gather-aggregate + bias + relu ----------------
// 2 edges per gather instruction: 32 lanes per edge, 8B (4 halves) per lane.
// sub = lane>>5 picks the edge of the pair; cq = lane&31 owns cols cq*4..cq*4+3.
// 4-pair (8-edge) software pipeline; __shfl_xor(32) reduce; persistent blocks.
__device__ __forceinline__ float4 gload(const __half* __restrict__ g, int idx, int cq) {
    uint2 u = *(const uint2*)(g + (size_t)idx * DD + cq * 4);
    __half2 h0 = *reinterpret_cast<const __half2*>(&u.x);
    __half2 h1 = *reinterpret_cast<const __half2*>(&u.y);
    float2 f0 = __half22float2(h0);
    float2 f1 = __half22float2(h1);
    return make_float4(f0.x, f0.y, f1.x, f1.y);
}

template <typename OutT>
__global__ __launch_bounds__(256) void agg_kernel(
    const __half* __restrict__ g, const float* __restrict__ dinv,
    const int* __restrict__ off, const int* __restrict__ csr,
    const float* __restrict__ bias, OutT* __restrict__ out)
{
    const int wid  = threadIdx.x >> 6;
    const int lane = threadIdx.x & 63;
    const int sub  = lane >> 5;       // which edge of the pair
    const int cq   = lane & 31;       // 8B chunk within the row
    const float4 bb = ((const float4*)bias)[cq];
    const int ngroups = (NN + 3) / 4;

    for (int grp = blockIdx.x; grp < ngroups; grp += AGG_BLOCKS) {
        int node = grp * 4 + wid;
        if (node >= NN) continue;

        float4 acc = make_float4(0.f, 0.f, 0.f, 0.f);
        float4 acc2 = make_float4(0.f, 0.f, 0.f, 0.f);
        if (sub == 0) acc = gload(g, node, cq);       // self-loop

        const int e0 = off[node], end = off[node + 1];
        const int cnt = end - e0;
        const int pairs = cnt >> 1;
        const int np4 = pairs & ~3;

        if (np4) {
            int i0 = csr[e0 + 0 + sub];
            int i1 = csr[e0 + 2 + sub];
            int i2 = csr[e0 + 4 + sub];
            int i3 = csr[e0 + 6 + sub];
            for (int p = 4; p < np4; p += 4) {
                int b0 = e0 + 2 * p + sub;
                int j0 = csr[b0];
                int j1 = csr[b0 + 2];
                int j2 = csr[b0 + 4];
                int j3 = csr[b0 + 6];
                float4 v0 = gload(g, i0, cq);
                float4 v1 = gload(g, i1, cq);
                float4 v2 = gload(g, i2, cq);
                float4 v3 = gload(g, i3, cq);
                acc.x += v0.x + v2.x; acc.y += v0.y + v2.y;
                acc.z += v0.z + v2.z; acc.w += v0.w + v2.w;
                acc2.x += v1.x + v3.x; acc2.y += v1.y + v3.y;
                acc2.z += v1.z + v3.z; acc2.w += v1.w + v3.w;
                i0 = j0; i1 = j1; i2 = j2; i3 = j3;
            }
            float4 v0 = gload(g, i0, cq);
            float4 v1 = gload(g, i1, cq);
            float4 v2 = gload(g, i2, cq);
            float4 v3 = gload(g, i3, cq);
            acc.x += v0.x + v2.x; acc.y += v0.y + v2.y;
            acc.z += v0.z + v2.z; acc.w += v0.w + v2.w;
            acc2.x += v1.x + v3.x; acc2.y += v1.y + v3.y;
            acc2.z += v1.z + v3.z; acc2.w += v1.w + v3.w;
        }
        for (int q = np4; q < pairs; ++q) {
            int s = csr[e0 + 2 * q + sub];
            float4 v = gload(g, s, cq);
            acc.x += v.x; acc.y += v.y; acc.z += v.z; acc.w += v.w;
        }
        if ((cnt & 1) && sub == 0) {
            int s = csr[end - 1];
            float4 v = gload(g, s, cq);
            acc.x += v.x; acc.y += v.y; acc.z += v.z; acc.w += v.w;
        }

        acc.x += acc2.x; acc.y += acc2.y; acc.z += acc2.z; acc.w += acc2.w;
        acc.x += __shfl_xor(acc.x, 32, 64);
        acc.y += __shfl_xor(acc.y, 32, 64);
        acc.z += __shfl_xor(acc.z, 32, 64);
        acc.w += __shfl_xor(acc.w, 32, 64);

        if (sub == 0) {
            float di = dinv[node];
            float4 o;
            o.x = fmaxf(fmaf(acc.x, di, bb.x), 0.f);
            o.y = fmaxf(fmaf(acc.y, di, bb.y), 0.f);
            o.z = fmaxf(fmaf(acc.z, di, bb.z), 0.f);
            o.w = fmaxf(fmaf(acc.w, di, bb.w), 0.f);
            if constexpr (sizeof(OutT) == 4) {
                ((float4*)out)[(size_t)node * 32 + cq] = o;
            } else {
                uint2 st;
                __half2 h0 = __floats2half2_rn(o.x, o.y);
                __half2 h1 = __floats2half2_rn(o.z, o.w);
                st.x = *reinterpret_cast<unsigned int*>(&h0);
                st.y = *reinterpret_cast<unsigned int*>(&h1);
                *(uint2*)((__half*)out + (size_t)node * DD + cq * 4) = st;
            }
        }
    }
}

extern "C" void kernel_launch(void* const* d_in, const int* in_sizes, int n_in,
                              void* d_out, int out_size, void* d_ws, size_t ws_size,
                              hipStream_t stream)
{
    const float* x  = (const float*)d_in[0];
    const float* W1 = (const float*)d_in[1];
    const float* b1 = (const float*)d_in[2];
    const float* W2 = (const float*)d_in[3];
    const float* b2 = (const float*)d_in[4];
    const float* W3 = (const float*)d_in[5];
    const float* b3 = (const float*)d_in[6];
    const int*   ei = (const int*)d_in[7];

    const int E = in_sizes[7] / 2;          // 1,600,000
    const int* src = ei;
    const int* dst = ei + E;

    float* out = (float*)d_out;

    // ---- workspace layout ----
    char* wsb = (char*)d_ws;
    size_t p = 0;
    int* deg      = (int*)(wsb + p); p += ((size_t)NN * 4 + 1023) & ~1023ull;
    int* offsets  = (int*)(wsb + p); p += ((size_t)(NN + 1) * 4 + 1023) & ~1023ull;
    int* chunkSum = (int*)(wsb + p); p += 4096;
    int* chunkOff = (int*)(wsb + p); p += 4096;
    int* csr      = (int*)(wsb + p); p += ((size_t)E * 4 + 1023) & ~1023ull;
    int* rank     = (int*)(wsb + p); p += ((size_t)E * 4 + 1023) & ~1023ull;
    float* dinv   = (float*)(wsb + p); p += ((size_t)NN * 4 + 1023) & ~1023ull;
    uint4* wh     = (uint4*)(wsb + p); p += 3 * 2048 * sizeof(uint4);
    uint4* wl     = (uint4*)(wsb + p); p += 3 * 2048 * sizeof(uint4);
    __half* g     = (__half*)(wsb + p); p += (size_t)NN * DD * 2;
    __half* h_act = (__half*)(wsb + p); p += (size_t)NN * DD * 2;

    const int NB = (NN + SCAN_CHUNK - 1) / SCAN_CHUNK;   // 49

    // ---- CSR build + dinv + W pre-split ----
    hipMemsetAsync(deg, 0, (size_t)NN * 4, stream);
    hist_rank_kernel<<<(E / 4 + 256) / 256 + 1, 256, 0, stream>>>(dst, E, deg, rank);
    scan1_kernel<<<NB, 256, 0, stream>>>(deg, chunkSum, dinv, NN);
    scan2_kernel<<<1, 512, 0, stream>>>(chunkSum, chunkOff, NB, offsets);
    scan3_kernel<<<NB, 256, 0, stream>>>(deg, chunkOff, offsets, NN);
    fill_kernel<<<(E / 4 + 256) / 256 + 1, 256, 0, stream>>>(src, dst, rank, E, offsets, csr);
    wsplit3_kernel<<<24, 256, 0, stream>>>(W1, W2, W3, wh, wl);

    const int gemm_grid = (NN + 127) / 128;               // 782

    // ---- layer 1 ----
    gemm_norm_kernel<float><<<gemm_grid, 256, 0, stream>>>(x, wh, wl, dinv, g);
    agg_kernel<__half><<<AGG_BLOCKS, 256, 0, stream>>>(g, dinv, offsets, csr, b1, h_act);
    // ---- layer 2 ----
    gemm_norm_kernel<__half><<<gemm_grid, 256, 0, stream>>>(h_act, wh + 2048, wl + 2048, dinv, g);
    agg_kernel<__half><<<AGG_BLOCKS, 256, 0, stream>>>(g, dinv, offsets, csr, b2, h_act);
    // ---- layer 3 ----
    gemm_norm_kernel<__half><<<gemm_grid, 256, 0, stream>>>(h_act, wh + 4096, wl + 4096, dinv, g);
    agg_kernel<float><<<AGG_BLOCKS, 256, 0, stream>>>(g, dinv, offsets, csr, b3, out);
}